// Round 12
// baseline (156.779 us; speedup 1.0000x reference)
//
#include <hip/hip_runtime.h>

// x: (2,8,256,256) fp32, F: 3x3 fp32.
#define HS 256
#define WSZ 256
#define NPIX (HS * WSZ)        // 65536 pixels
#define NCH 16                 // B*C
#define NELEM (NPIX * NCH)
#define PSTRIDE 257            // s-slots (0..256) per row of P
#define PLINES (HS * PSTRIDE)  // number of (h,s) 64B lines in P
#define ZLINE  PLINES          // spare zeroed line (invalid-row target)

// ---------------------------------------------------------------------------
// Prefix kernel: P[h][s][ch] = sum_{w<s} x[ch][h][w], s in [0,256].
// Layout (h, s, ch): one (h,s) boundary's 16 channels = one 64B line.
// Also zeroes the spare ZLINE. Rebuilt every launch (d_ws re-poisoned).
// ---------------------------------------------------------------------------
__global__ __launch_bounds__(256) void prefix_kernel(const float* __restrict__ x,
                                                     float* __restrict__ P) {
    int h   = blockIdx.x;
    int t   = threadIdx.x;
    int c   = t >> 4;
    int seg = t & 15;

    const float4* row4 = (const float4*)(x + (size_t)c * NPIX + h * WSZ + seg * 16);
    float4 v0 = row4[0], v1 = row4[1], v2 = row4[2], v3 = row4[3];
    float vals[16] = {v0.x, v0.y, v0.z, v0.w, v1.x, v1.y, v1.z, v1.w,
                      v2.x, v2.y, v2.z, v2.w, v3.x, v3.y, v3.z, v3.w};

    float seg_sum = 0.0f;
#pragma unroll
    for (int k = 0; k < 16; ++k) seg_sum += vals[k];

    float incl = seg_sum;
#pragma unroll
    for (int d = 1; d < 16; d <<= 1) {
        float o = __shfl_up(incl, d, 16);
        if (seg >= d) incl += o;
    }
    float run = incl - seg_sum;    // exclusive prefix at s = seg*16

    float* Pr = P + (size_t)h * PSTRIDE * NCH;
    if (seg == 0) Pr[c] = 0.0f;
    if (h == 0 && t < NCH) P[(size_t)ZLINE * NCH + t] = 0.0f;  // zero line
    int s0 = seg * 16;
#pragma unroll
    for (int k = 0; k < 16; ++k) {
        run += vals[k];
        Pr[(s0 + k + 1) * NCH + c] = run;
    }
}

// ---------------------------------------------------------------------------
// Geometry (bit-exact, verified R6): FMA-contracted einsum, f32.
// ---------------------------------------------------------------------------
struct LineGeom {
    float p, q, c;
    bool  col;
};

__device__ __forceinline__ LineGeom make_geom(const float* __restrict__ F, int pix) {
#pragma clang fp contract(off)
    int w = pix & (WSZ - 1);
    int h = pix >> 8;
    float u = (float)w, v = (float)h;
    float a = __builtin_fmaf(F[3], v, F[0] * u) + F[6];
    float b = __builtin_fmaf(F[4], v, F[1] * u) + F[7];
    float c = __builtin_fmaf(F[5], v, F[2] * u) + F[8];
    const float eps = 1e-8f;
    float bs = (fabsf(b) < eps) ? eps : b;
    float as = (fabsf(a) < eps) ? eps : a;
    LineGeom g;
    g.col = (fabsf(b) >= fabsf(a));
    g.p   = g.col ? a : b;
    g.q   = g.col ? bs : as;
    g.c   = c;
    return g;
}

// Chain (bit-exact, verified R6): t = fma(p,s,c); y = (-t)/q IEEE f32; rint; i32.
__device__ __forceinline__ int chainY(const LineGeom& g, int s) {
#pragma clang fp contract(off)
    float t  = __builtin_fmaf(g.p, (float)s, g.c);
    float y  = (-t) / g.q;
    return (int)__builtin_rintf(y);
}

// ---------------------------------------------------------------------------
// Event-compacted prefix gather: ONE WAVE PER PIXEL.
// Lane computes the exact chain at s = it*64+lane; yprev via shfl_up(+carry);
// __ballot(yprev != y) gives a wave-uniform boundary mask consumed by a
// UNIFORM while-loop: per event, 2 readlanes deliver (y_prev, y_cur) and
// lanes 0..7 load +/-P at the boundary (2 cache lines; idle lanes masked).
// Telescoped sum: out = sum_bnd [P(yprev,s) - P(ycur,s)] + P(y255,256),
// with P(invalid,.) -> zeroed spare line. Only summation grouping differs
// from the per-sample reference; index decisions are bit-identical.
// ---------------------------------------------------------------------------
__global__ __launch_bounds__(256) void epi_gather_evt(const float4* __restrict__ P4,
                                                      const float* __restrict__ x,
                                                      const float* __restrict__ F,
                                                      float* __restrict__ out) {
    int wid  = (blockIdx.x * 256 + threadIdx.x) >> 6;   // wave id == pixel
    int lane = threadIdx.x & 63;
    int pix  = wid;

    LineGeom g = make_geom(F, pix);
    float4 acc = make_float4(0.f, 0.f, 0.f, 0.f);
    int cq = lane & 3;

    if (g.col) {
        const int zeroIdx = ZLINE * 4 + cq;
        int carry = (int)0x80000000;        // sentinel: "y(-1)", never valid

        for (int it = 0; it < 4; ++it) {
            int base = it << 6;
            int y    = chainY(g, base + lane);
            int yup  = __shfl_up(y, 1, 64);
            int yprev = (lane == 0) ? carry : yup;
            carry = __shfl(y, 63, 64);      // y at last slot, next iter's carry

            unsigned long long m = __ballot(yprev != y);
            while (m) {
                int se = __ffsll(m) - 1;    // uniform: lowest event slot
                m &= m - 1;
                int ya = __shfl(yprev, se, 64);   // readlane (uniform idx)
                int yb = __shfl(y,     se, 64);
                if (lane < 8) {
                    int  yr  = (lane < 4) ? ya : yb;
                    int  sg  = base + se;
                    int  idx = ((unsigned)yr < 256u) ? ((yr * PSTRIDE + sg) * 4 + cq)
                                                     : zeroIdx;
                    float4 p = P4[idx];
                    if (lane < 4) { acc.x += p.x; acc.y += p.y; acc.z += p.z; acc.w += p.w; }
                    else          { acc.x -= p.x; acc.y -= p.y; acc.z -= p.z; acc.w -= p.w; }
                }
            }
        }
        // tail: + P(y(255), 256)
        if (lane < 4 && (unsigned)carry < 256u) {
            float4 p = P4[(carry * PSTRIDE + 256) * 4 + cq];
            acc.x += p.x; acc.y += p.y; acc.z += p.z; acc.w += p.w;
        }

        // fold minus-half (lanes 4..7) into plus-half (lanes 0..3)
        acc.x += __shfl_xor(acc.x, 4, 64);
        acc.y += __shfl_xor(acc.y, 4, 64);
        acc.z += __shfl_xor(acc.z, 4, 64);
        acc.w += __shfl_xor(acc.w, 4, 64);

        if (lane < 4) {
            int ch = cq * 4;
            out[(ch + 0) * NPIX + pix] = acc.x;
            out[(ch + 1) * NPIX + pix] = acc.y;
            out[(ch + 2) * NPIX + pix] = acc.z;
            out[(ch + 3) * NPIX + pix] = acc.w;
        }
    } else {
        // Row mode (never taken for this F; slow-but-correct generic path):
        // lane ch<16 sums x[ch][s][xi(s)] over all s.
        if (lane < 16) {
            float a = 0.0f;
            for (int s = 0; s < 256; ++s) {
                int xi = chainY(g, s);
                if ((unsigned)xi < 256u) a += x[lane * NPIX + s * WSZ + xi];
            }
            out[lane * NPIX + pix] = a;
        }
    }
}

// ---------------------------------------------------------------------------
// Fallback without workspace: direct per-sample gathers from (bc,h,w).
// ---------------------------------------------------------------------------
__device__ __forceinline__ int sample_row(const LineGeom& g, int s) {
#pragma clang fp contract(off)
    float sf = (float)s;
    float t  = __builtin_fmaf(g.p, sf, g.c);
    float y  = (-t) / g.q;
    float yr = __builtin_rintf(y);
    int   yi = (int)yr;
    return (yi >= 0 && yi < HS) ? yi : -1;
}

__global__ __launch_bounds__(256) void epi_gather_direct(const float* __restrict__ x,
                                                         const float* __restrict__ F,
                                                         float* __restrict__ out) {
    int tid  = blockIdx.x * 256 + threadIdx.x;
    int quad = tid & 3;
    int pix  = tid >> 2;

    LineGeom g = make_geom(F, pix);

    float4 acc = make_float4(0.f, 0.f, 0.f, 0.f);
    int base = quad * 4;

#pragma unroll 2
    for (int s = 0; s < 256; ++s) {
        int  t     = sample_row(g, s);
        bool valid = (t >= 0);
        int  tcl   = valid ? t : 0;
        int  addr  = g.col ? (tcl * WSZ + s) : (s * WSZ + tcl);
        if (valid) {
            acc.x += x[(base + 0) * NPIX + addr];
            acc.y += x[(base + 1) * NPIX + addr];
            acc.z += x[(base + 2) * NPIX + addr];
            acc.w += x[(base + 3) * NPIX + addr];
        }
    }

    out[(base + 0) * NPIX + pix] = acc.x;
    out[(base + 1) * NPIX + pix] = acc.y;
    out[(base + 2) * NPIX + pix] = acc.z;
    out[(base + 3) * NPIX + pix] = acc.w;
}

extern "C" void kernel_launch(void* const* d_in, const int* in_sizes, int n_in,
                              void* d_out, int out_size, void* d_ws, size_t ws_size,
                              hipStream_t stream) {
    const float* x   = (const float*)d_in[0];
    const float* F   = (const float*)d_in[1];
    float*       out = (float*)d_out;

    const size_t need = (size_t)(PLINES + 1) * NCH * sizeof(float);  // ~4.21 MB
    if (ws_size >= need) {
        float* P = (float*)d_ws;
        prefix_kernel<<<HS, 256, 0, stream>>>(x, P);
        epi_gather_evt<<<(NPIX * 64) / 256, 256, 0, stream>>>((const float4*)P, x, F, out);
    } else {
        epi_gather_direct<<<(NPIX * 4) / 256, 256, 0, stream>>>(x, F, out);
    }
}

// Round 14
// 93.607 us; speedup vs baseline: 1.6749x; 1.6749x over previous
//
#include <hip/hip_runtime.h>

// x: (2,8,256,256) fp32, F: 3x3 fp32.
#define HS 256
#define WSZ 256
#define NPIX (HS * WSZ)        // 65536 pixels
#define NCH 16                 // B*C
#define NELEM (NPIX * NCH)

typedef float f4 __attribute__((ext_vector_type(4)));

// ---------------------------------------------------------------------------
// Transpose (bc, h, w) -> (h, w, bc), LDS-tiled, coalesced both sides.
// Also zeroes a 512 B pad at T[NELEM..NELEM+128) — the invalid-sample target
// (wide enough for any immediate-offset load). Rebuilt every launch.
// ---------------------------------------------------------------------------
__global__ __launch_bounds__(256) void transpose_kernel(const float* __restrict__ x,
                                                        float* __restrict__ T) {
    __shared__ float lds[16][257];   // +1 pad
    int tid  = threadIdx.x;
    int base = blockIdx.x * 256;
#pragma unroll
    for (int ch = 0; ch < 16; ++ch)
        lds[ch][tid] = x[ch * NPIX + base + tid];   // coalesced 1KB per instr
    if (blockIdx.x == 0 && tid < 128) T[NELEM + tid] = 0.0f;  // zero pad
    __syncthreads();
    float4* T4 = (float4*)T;
#pragma unroll
    for (int it = 0; it < 4; ++it) {
        int idx = it * 256 + tid;    // 0..1023 float4s of this tile
        int p   = idx >> 2;          // local pixel
        int q   = idx & 3;           // channel quad
        float4 o;
        o.x = lds[q * 4 + 0][p];
        o.y = lds[q * 4 + 1][p];
        o.z = lds[q * 4 + 2][p];
        o.w = lds[q * 4 + 3][p];
        T4[base * 4 + idx] = o;      // contiguous 16B/lane -> coalesced
    }
}

// ---------------------------------------------------------------------------
// Geometry (bit-exact, verified R6): FMA-contracted einsum, f32.
// ---------------------------------------------------------------------------
struct LineGeom {
    float p, q, c;
    bool  col;
};

__device__ __forceinline__ LineGeom make_geom(const float* __restrict__ F, int pix) {
#pragma clang fp contract(off)
    int w = pix & (WSZ - 1);
    int h = pix >> 8;
    float u = (float)w, v = (float)h;
    float a = __builtin_fmaf(F[3], v, F[0] * u) + F[6];
    float b = __builtin_fmaf(F[4], v, F[1] * u) + F[7];
    float c = __builtin_fmaf(F[5], v, F[2] * u) + F[8];
    const float eps = 1e-8f;
    float bs = (fabsf(b) < eps) ? eps : b;
    float as = (fabsf(a) < eps) ? eps : a;
    LineGeom g;
    g.col = (fabsf(b) >= fabsf(a));
    g.p   = g.col ? a : b;
    g.q   = g.col ? bs : as;
    g.c   = c;
    return g;
}

// Chain (bit-exact, verified R6): t = fma(p,s,c); y = (-t)/q IEEE f32; rint.
// Returns the RAW rounded integer; validity tested as (unsigned)y < 256u.
__device__ __forceinline__ int chainY(const LineGeom& g, int s) {
#pragma clang fp contract(off)
    float t  = __builtin_fmaf(g.p, (float)s, g.c);
    float y  = (-t) / g.q;
    return (int)__builtin_rintf(y);
}

// ---------------------------------------------------------------------------
// Gather (R9 structure, VALU-trimmed): 16 threads/pixel = quad(4) x sq(4).
// Thread computes s%4==quad chains of its 64-sample quarter, DPP-broadcasts
// the row to its quad group; col-specialized addressing: float4 index =
// (y<<10) | (s<<2) | quad, with the per-j step (+4 float4s per sample)
// folded into the load's immediate offset; invalid rows redirect into the
// 512 B zero pad (compensated for the imm). 8-deep load batches for MLP.
// ---------------------------------------------------------------------------
#define QUAD_BCAST(dst, src, ctrl)                                              \
    dst = __builtin_amdgcn_mov_dpp(src, ctrl, 0xf, 0xf, false)

__global__ __launch_bounds__(256) void epi_gather(const f4* __restrict__ T4,
                                                  const float* __restrict__ x,
                                                  const float* __restrict__ F,
                                                  float* __restrict__ out) {
    int tid  = blockIdx.x * 256 + threadIdx.x;
    int quad = tid & 3;
    int sq   = (tid >> 2) & 3;           // s-quarter
    int pix  = tid >> 4;

    LineGeom g = make_geom(F, pix);
    f4 acc = {0.f, 0.f, 0.f, 0.f};

    if (g.col) {
        const int zeroF4 = NPIX * 4 + quad;  // start of zero pad (512 B = 32 f4)
        int schain = (sq << 6) + quad;       // s of my chains: sq*64 + quad + 4k
        int sPart  = ((sq << 6) << 2) | quad;  // (s<<2)|quad for j=0 of batch

#pragma unroll 2
        for (int m = 0; m < 8; ++m) {
            int t0 = chainY(g, schain); schain += 4;
            int t1 = chainY(g, schain); schain += 4;
            int fb[8];
            int tj;
            // fb[j] excludes the per-sample +4*J f4-step; that folds into the
            // load's immediate offset (zero redirect compensates).
#define IDX(J, SRC, CTRL)                                                       \
            QUAD_BCAST(tj, SRC, CTRL);                                          \
            fb[J] = (tj << 10) | sPart;                                         \
            fb[J] = ((unsigned)tj < 256u) ? fb[J] : (zeroF4 - 4 * (J));
            IDX(0, t0, 0x00) IDX(1, t0, 0x55) IDX(2, t0, 0xAA) IDX(3, t0, 0xFF)
            IDX(4, t1, 0x00) IDX(5, t1, 0x55) IDX(6, t1, 0xAA) IDX(7, t1, 0xFF)
#undef IDX
            // batch-issue 8 independent 16B loads, +4*J folded as imm offset
            f4 v0 = T4[fb[0] +  0], v1 = T4[fb[1] +  4];
            f4 v2 = T4[fb[2] +  8], v3 = T4[fb[3] + 12];
            f4 v4 = T4[fb[4] + 16], v5 = T4[fb[5] + 20];
            f4 v6 = T4[fb[6] + 24], v7 = T4[fb[7] + 28];
            // ascending-s accumulate (vector adds -> v_pk_add_f32)
            acc += v0; acc += v1; acc += v2; acc += v3;
            acc += v4; acc += v5; acc += v6; acc += v7;
            sPart += 32;                     // 8 samples * 4 f4/sample
        }
    } else {
        // Row mode (never taken for this F; generic correctness): per-sample
        // scalar gathers from x over this thread's quarter.
        int lo = sq << 6;
        int ch = quad * 4;
        for (int s = lo; s < lo + 64; ++s) {
            int xi = chainY(g, s);
            if ((unsigned)xi < 256u) {
                int addr = s * WSZ + xi;
                acc.x += x[(ch + 0) * NPIX + addr];
                acc.y += x[(ch + 1) * NPIX + addr];
                acc.z += x[(ch + 2) * NPIX + addr];
                acc.w += x[(ch + 3) * NPIX + addr];
            }
        }
    }

    // merge the four s-quarters (same order as the passing R9: xor8, xor4)
    acc.x += __shfl_xor(acc.x, 8, 64);
    acc.y += __shfl_xor(acc.y, 8, 64);
    acc.z += __shfl_xor(acc.z, 8, 64);
    acc.w += __shfl_xor(acc.w, 8, 64);
    acc.x += __shfl_xor(acc.x, 4, 64);
    acc.y += __shfl_xor(acc.y, 4, 64);
    acc.z += __shfl_xor(acc.z, 4, 64);
    acc.w += __shfl_xor(acc.w, 4, 64);

    if (sq == 0) {
        int ch = quad * 4;
        out[(ch + 0) * NPIX + pix] = acc.x;
        out[(ch + 1) * NPIX + pix] = acc.y;
        out[(ch + 2) * NPIX + pix] = acc.z;
        out[(ch + 3) * NPIX + pix] = acc.w;
    }
}

// ---------------------------------------------------------------------------
// Fallback without workspace: direct per-sample gathers from (bc,h,w).
// ---------------------------------------------------------------------------
__global__ __launch_bounds__(256) void epi_gather_direct(const float* __restrict__ x,
                                                         const float* __restrict__ F,
                                                         float* __restrict__ out) {
    int tid  = blockIdx.x * 256 + threadIdx.x;
    int quad = tid & 3;
    int pix  = tid >> 2;

    LineGeom g = make_geom(F, pix);

    float4 acc = make_float4(0.f, 0.f, 0.f, 0.f);
    int base = quad * 4;

#pragma unroll 2
    for (int s = 0; s < 256; ++s) {
        int  yi    = chainY(g, s);
        bool valid = ((unsigned)yi < 256u);
        int  tcl   = valid ? yi : 0;
        int  addr  = g.col ? (tcl * WSZ + s) : (s * WSZ + tcl);
        if (valid) {
            acc.x += x[(base + 0) * NPIX + addr];
            acc.y += x[(base + 1) * NPIX + addr];
            acc.z += x[(base + 2) * NPIX + addr];
            acc.w += x[(base + 3) * NPIX + addr];
        }
    }

    out[(base + 0) * NPIX + pix] = acc.x;
    out[(base + 1) * NPIX + pix] = acc.y;
    out[(base + 2) * NPIX + pix] = acc.z;
    out[(base + 3) * NPIX + pix] = acc.w;
}

extern "C" void kernel_launch(void* const* d_in, const int* in_sizes, int n_in,
                              void* d_out, int out_size, void* d_ws, size_t ws_size,
                              hipStream_t stream) {
    const float* x   = (const float*)d_in[0];
    const float* F   = (const float*)d_in[1];
    float*       out = (float*)d_out;

    const size_t need = (size_t)(NELEM + 128) * sizeof(float);
    if (ws_size >= need) {
        float* T = (float*)d_ws;
        transpose_kernel<<<NPIX / 256, 256, 0, stream>>>(x, T);
        epi_gather<<<(NPIX * 16) / 256, 256, 0, stream>>>((const f4*)T, x, F, out);
    } else {
        epi_gather_direct<<<(NPIX * 4) / 256, 256, 0, stream>>>(x, F, out);
    }
}